// Round 3
// baseline (83.118 us; speedup 1.0000x reference)
//
#include <hip/hip_runtime.h>
#include <math.h>

// PCEN: x [16,1,128,2048] f32, params alpha/delta/r [128] (log-space).
// smoother m[t] = (1-s) m[t-1] + s x[t], m[-1] = x[0]  (== reference's dense
// triangular matmul, verified algebraically).
// out[b, t, band] = (x*smooth + d)^rr - d^rr
//
// R3: same scan/fixup/writeout as R2 (16 waves = 8 bands x 2 T-halves).
// Load path changed: block's 8 band-rows are 64KB CONTIGUOUS -> stage via
// LDS with dense thread-linear float4 loads (16 lines/instr, 4 lanes/line
// merged) instead of 64B-lane-strided loads (64 lines/instr, 16B used each).
// LDS stage XOR-swizzled (w ^= ((w>>5)&7)<<2): conflict-free linear write
// AND conflict-free per-lane contiguous b128 read. Stage buffer aliases the
// output tile (stage read completes before fixup overwrites; the carry
// barrier covers it).

#define T_LEN   2048
#define NBANDS  128
#define PL      2184   // tile plane stride (words): 128*17 + 8 pad

__global__ __launch_bounds__(1024) void pcen_kernel(
    const float* __restrict__ x,
    const float* __restrict__ alpha,
    const float* __restrict__ delta,
    const float* __restrict__ r,
    float* __restrict__ out)
{
    __shared__ __align__(16) float lds[8 * PL];   // 69.9 KB; first 16384 words = x stage
    __shared__ float carr[8];

    const int tid  = threadIdx.x;
    const int w    = tid >> 6;     // wave 0..15
    const int lane = tid & 63;
    const int wb   = w & 7;        // band within group
    const int h    = w >> 3;       // T-half 0/1
    const int bid  = blockIdx.x;
    const int b    = bid >> 4;
    const int bg   = bid & 15;
    const int band = bg * 8 + wb;

    const float s = (sqrtf(262145.0f) - 1.0f) / 131072.0f;
    const float g = 1.0f - s;
    float g16 = g * g;   // ^2
    g16 *= g16;          // ^4
    g16 *= g16;          // ^8
    g16 *= g16;          // ^16

    const float a    = __expf(alpha[band]);
    const float dd   = __expf(delta[band]);
    const float rr   = __expf(r[band]);
    const float dpow = __expf(rr * delta[band]);   // d^rr
    const float LOG_EPS = -11.512925465f;          // log(1e-5)
    const float INV_EPS = 1.0e5f;

    // ---- dense staged load: 64KB contiguous block -> LDS (swizzled) ----
    const float4* xblk = reinterpret_cast<const float4*>(
        x + ((size_t)b * NBANDS + bg * 8) * T_LEN);
    #pragma unroll
    for (int j = 0; j < 4; ++j) {
        const int e  = j * 1024 + tid;              // float4 index 0..4095
        const float4 v = xblk[e];
        const int w0 = e * 4;                        // word index
        const int sz = w0 ^ (((w0 >> 5) & 7) << 2);  // XOR swizzle (bits 2..4)
        *reinterpret_cast<float4*>(&lds[sz]) = v;
    }
    __syncthreads();

    // ---- each lane reads its contiguous 16-elem chunk (conflict-free) ----
    float xs[16];
    const int base = wb * 2048 + h * 1024 + lane * 16;
    #pragma unroll
    for (int k = 0; k < 4; ++k) {
        const int w0 = base + k * 4;
        const int sz = w0 ^ (((w0 >> 5) & 7) << 2);
        const float4 v = *reinterpret_cast<const float4*>(&lds[sz]);
        xs[k*4+0] = v.x; xs[k*4+1] = v.y; xs[k*4+2] = v.z; xs[k*4+3] = v.w;
    }

    // ---- local serial scan for lane carry (h0/lane0 seeds m[-1] = x[0]) ----
    float m = (h == 0 && lane == 0) ? xs[0] : 0.0f;
    #pragma unroll
    for (int k = 0; k < 16; ++k) m = fmaf(g, m, s * xs[k]);

    // ---- decayed Kogge-Stone inclusive scan of lane carries ----
    float v = m;
    float f = g16;
    #pragma unroll
    for (int off = 1; off < 64; off <<= 1) {
        float u = __shfl_up(v, off, 64);
        if (lane >= off) v = fmaf(f, u, v);
        f = f * f;
    }
    float carry = __shfl_up(v, 1, 64);
    if (lane == 0) carry = (h == 0) ? xs[0] : 0.0f;

    // ---- cross-half carry; barrier also fences stage reads vs tile writes --
    if (h == 0 && lane == 63) carr[wb] = v;
    __syncthreads();
    if (h == 1) {
        const float m1023 = carr[wb];
        const float lng16 = __logf(g16);
        const float scale = __expf((float)lane * lng16);  // g^(16*lane)
        carry = fmaf(scale, m1023, carry);
    }

    // ---- fixup + pcen + LDS transpose stage ----
    float* tw = lds + wb * PL + (h * 64 + lane) * 17;
    m = carry;
    #pragma unroll
    for (int k = 0; k < 16; ++k) {
        m = fmaf(g, m, s * xs[k]);                         // smoother[t]
        float lg     = LOG_EPS + __logf(fmaf(m, INV_EPS, 1.0f));
        float smooth = __expf(-a * lg);
        float base2  = fmaf(xs[k], smooth, dd);
        float o      = __expf(rr * __logf(base2)) - dpow;
        tw[k] = o;
    }
    __syncthreads();

    // ---- t-major coalesced write: out[b][t][band] ----
    const int wp  = tid & 7;
    const int tof = tid >> 3;
    float* op = out + (size_t)b * T_LEN * NBANDS + bg * 8;
    #pragma unroll 4
    for (int c = 0; c < 16; ++c) {
        int t = c * 128 + tof;
        int l = t >> 4;
        int k = t & 15;
        op[(size_t)t * NBANDS + wp] = lds[wp * PL + l * 17 + k];
    }
}

extern "C" void kernel_launch(void* const* d_in, const int* in_sizes, int n_in,
                              void* d_out, int out_size, void* d_ws, size_t ws_size,
                              hipStream_t stream) {
    const float* x     = (const float*)d_in[0];
    const float* alpha = (const float*)d_in[1];
    const float* delta = (const float*)d_in[2];
    const float* r     = (const float*)d_in[3];
    float* out = (float*)d_out;

    hipLaunchKernelGGL(pcen_kernel, dim3(16 * 16), dim3(1024), 0, stream,
                       x, alpha, delta, r, out);
}